// Round 6
// baseline (604.439 us; speedup 1.0000x reference)
//
#include <hip/hip_runtime.h>
#include <cstdint>
#include <cstddef>

typedef unsigned short u16;
typedef unsigned int   u32;
typedef __attribute__((ext_vector_type(8)))  short bf16x8;
typedef __attribute__((ext_vector_type(16))) float f32x16;

#define NB   16
#define LL   1024
#define CIN  300
#define CINP 320              /* padded channels: rows 640B, 16B aligned */
#define XPBP (LL*CINP)        /* 327680 elems per batch */
#define XELP (NB*XPBP)        /* 5242880 */
#define NCH  6000
#define NCHP 6144             /* padded to 24*256 */
#define ODIM 100
#define OUTN (NB*ODIM*180)    /* 288000 */

#define BM 256
#define BN 256
#define BK 64

__device__ __forceinline__ u16 f2bf(float f) {
  union { float f; u32 u; } v; v.f = f;
  return (u16)((v.u + 0x7FFFu + ((v.u >> 16) & 1u)) >> 16);   // RNE, inputs finite
}

typedef __attribute__((address_space(1))) const unsigned int gu32;
typedef __attribute__((address_space(3))) unsigned int lu32;
__device__ __forceinline__ void gload_lds16(const void* g, void* l) {
  __builtin_amdgcn_global_load_lds((gu32*)g, (lu32*)l, 16, 0, 0);
}

#define BAR() asm volatile("s_barrier" ::: "memory")

// ---- zero d_out (atomicMax identity; relu outputs are >= 0) --------------
__global__ void zero_out_kernel(float* __restrict__ out) {
  int i = blockIdx.x * 256 + threadIdx.x;
  if (i < OUTN) out[i] = 0.f;
}

// ---- x [16,1024,300] f32 -> xb [16,1024,320] bf16 (zero-pad channels) ----
__global__ void cvt_x_kernel(const float* __restrict__ x, u16* __restrict__ xb) {
  int i8 = (blockIdx.x * 256 + threadIdx.x) * 8;   // grid = XELP/(256*8) = 2560
  int row = i8 / CINP;
  int col = i8 - row * CINP;
  const float* src = x + (size_t)row * CIN + col;
  u16 e[8];
  if (col + 8 <= CIN) {
    float4 a = *(const float4*)src;
    float4 b = *(const float4*)(src + 4);
    e[0]=f2bf(a.x); e[1]=f2bf(a.y); e[2]=f2bf(a.z); e[3]=f2bf(a.w);
    e[4]=f2bf(b.x); e[5]=f2bf(b.y); e[6]=f2bf(b.z); e[7]=f2bf(b.w);
  } else {
    #pragma unroll
    for (int j = 0; j < 8; j++)
      e[j] = (col + j < CIN) ? f2bf(src[j]) : (u16)0;
  }
  uint4 o;
  o.x = (u32)e[0] | ((u32)e[1] << 16);
  o.y = (u32)e[2] | ((u32)e[3] << 16);
  o.z = (u32)e[4] | ((u32)e[5] << 16);
  o.w = (u32)e[6] | ((u32)e[7] << 16);
  *(uint4*)(xb + i8) = o;
}

// ---- W[n,o,c,j] f32 -> Wb[no][kp = j*320 + c] bf16 (zeros c>=300, no>=6000)
__global__ void repack_w_kernel(const float* __restrict__ W2, const float* __restrict__ W3,
                                const float* __restrict__ W4, u16* __restrict__ wb) {
  int g = blockIdx.y;
  int kk = g + 2;
  int Kp = kk * CINP;
  int woff = (g == 0) ? 0 : (g == 1) ? NCHP*640 : NCHP*(640+960);
  const float* W = (g == 0) ? W2 : (g == 1) ? W3 : W4;
  int no = blockIdx.x;                       // 0..6143
  u16* dst = wb + (size_t)woff + (size_t)no * Kp;
  const float* src = W + (size_t)no * (CIN * kk);
  for (int kp = threadIdx.x; kp < Kp; kp += 256) {
    int j = kp / CINP, c = kp - j * CINP;
    u16 v = 0;
    if (no < NCH && c < CIN) v = f2bf(src[c * kk + j]);
    dst[kp] = v;
  }
}

// ---- fused GEMM + running-max + bias + relu -------------------------------
// 256^2 8-phase (T2+T3+T4+T5), mfma_32x32x16, t-split grid with atomicMax
// partial-combine:  relu(max(a1,a2)+b) = max(relu(a1+b), relu(a2+b)).
// Grid: 2304 blocks = 3 groups x 768 (each = 16 b x 24 chblk x 2 tpair),
// durations 40/30/20 K-steps; 3x256 of each -> perfect 270-unit/CU packing.
// Per phase: ds_read frags (swizzled) | 1 half-tile stage | BAR |
//            setprio(1) 8x MFMA-32x32 setprio(0) | counted vmcnt | BAR
// Steady vmcnt(4) at ph1/ph2/ph4; prologue vmcnt(4); last tile drains 2->0.
__global__ __launch_bounds__(512, 1)
void gemm_max_kernel(const u16* __restrict__ xb, const u16* __restrict__ wb,
                     const float* __restrict__ b2v, const float* __restrict__ b3v,
                     const float* __restrict__ b4v, float* __restrict__ out) {
  // LPT classes: ids 0..767 -> g=2 (40 steps), 768..1535 -> g=1 (30), rest g=0 (20)
  const int id  = blockIdx.x;
  const int g   = (id < 768) ? 2 : (id < 1536) ? 1 : 0;
  const int id2 = id - ((g == 2) ? 0 : (g == 1) ? 768 : 1536);
  const int b     = id2 / 48;
  const int rem   = id2 - b * 48;
  const int chblk = rem >> 1;      // 0..23
  const int tpair = rem & 1;       // 0..1 : t-tiles {2*tpair, 2*tpair+1}
  const int Kp    = (g + 2) * CINP;                 // 640 / 960 / 1280
  const int nks   = Kp >> 6;                        // 10 / 15 / 20
  const int woff  = (g == 0) ? 0 : (g == 1) ? NCHP*640 : NCHP*(640+960);
  const int Lt    = LL - (g + 2) + 1;

  __shared__ __align__(16) u16 smem[4 * 16384];     // 128 KiB
  u16* A0s = smem;
  u16* B0s = smem + 16384;
  u16* A1s = smem + 32768;
  u16* B1s = smem + 49152;

  const int tid  = threadIdx.x;
  const int lane = tid & 63;
  const int w    = tid >> 6;       // 0..7
  const int wr   = w >> 2;         // 0..1 : M interleave (32-row groups)
  const int wc   = w & 3;          // 0..3 : N interleave (32-col groups)

  const u16* __restrict__ xrow = xb + (size_t)b * XPBP;
  const u16* __restrict__ Wg   = wb + (size_t)woff + (size_t)chblk * BN * Kp;

  // stage one 128x64 half: linear LDS dest (wave-uniform base), inverse-swizzled src
  auto STAGE = [&](const u16* src, int stride, u16* buf, int half) {
    #pragma unroll
    for (int i = 0; i < 2; i++) {
      int c = i * 512 + w * 64 + lane;                  // chunk 0..1023
      int row128 = c >> 3;
      int colb = ((c & 7) * 16) ^ ((row128 & 7) << 4);  // inverse swizzle (involution)
      gload_lds16(src + (size_t)(half * 128 + row128) * stride + (colb >> 1),
                  buf + half * 8192 + i * 4096 + w * 512);
    }
  };

  // swizzled fragment read for 32x32x16: group grp (32 rows), k-slice ksl (16 elems)
  // lane l holds rows grp*32+(l&31), k = ksl*16 + (l>>5)*8 + e
  auto FR32 = [&](const u16* buf, int grp, int ksl) -> bf16x8 {
    int row  = grp * 32 + (lane & 31);
    int colb = (ksl * 32 + ((lane >> 5) << 4)) ^ ((lane & 7) << 4);
    return *(const bf16x8*)(buf + row * 64 + (colb >> 1));
  };

  f32x16 acc[4][2];
  #pragma unroll
  for (int a2 = 0; a2 < 4; a2++)
    #pragma unroll
    for (int b2 = 0; b2 < 2; b2++)
      #pragma unroll
      for (int q = 0; q < 16; q++)
        acc[a2][b2][q] = 0.f;

  bf16x8 afr[2][4];       // [a2loc][ksl] current A-half frags
  bf16x8 bfr[2][4];       // [b2=NH][ksl], both B halves held across MHC
  float rmax[2] = { -1e30f, -1e30f };

  // fold acc into running max (C/D map: col=lane&31, row=(r&3)+8*(r>>2)+4*(lane>>5))
  auto FOLD = [&](int ttg) {
    #pragma unroll
    for (int a2 = 0; a2 < 4; a2++) {
      int rowbase = ttg * 256 + (a2 * 2 + wr) * 32 + ((lane >> 5) << 2);
      #pragma unroll
      for (int r = 0; r < 16; r++) {
        int t = rowbase + (r & 3) + 8 * (r >> 2);
        bool ok = t < Lt;
        #pragma unroll
        for (int b2 = 0; b2 < 2; b2++) {
          if (ok) rmax[b2] = fmaxf(rmax[b2], acc[a2][b2][r]);
          acc[a2][b2][r] = 0.f;
        }
      }
    }
  };

#define PHASE(CA, CB, MHC, NH, RA, RB, STG, VM) do {                          \
    if (RA) {                                                                 \
      _Pragma("unroll")                                                       \
      for (int a2l = 0; a2l < 2; a2l++) {                                     \
        _Pragma("unroll")                                                     \
        for (int ksl = 0; ksl < 4; ksl++)                                     \
          afr[a2l][ksl] = FR32(CA, ((MHC)*2 + a2l) * 2 + wr, ksl);            \
      }                                                                       \
    }                                                                         \
    if (RB) {                                                                 \
      _Pragma("unroll")                                                       \
      for (int ksl = 0; ksl < 4; ksl++)                                       \
        bfr[NH][ksl] = FR32(CB, (NH)*4 + wc, ksl);                            \
    }                                                                         \
    STG;                                                                      \
    BAR();                                                                    \
    __builtin_amdgcn_s_setprio(1);                                            \
    _Pragma("unroll")                                                         \
    for (int ksl = 0; ksl < 4; ksl++)                                         \
      _Pragma("unroll")                                                       \
      for (int a2l = 0; a2l < 2; a2l++)                                       \
        acc[(MHC)*2 + a2l][NH] =                                              \
          __builtin_amdgcn_mfma_f32_32x32x16_bf16(afr[a2l][ksl],              \
            bfr[NH][ksl], acc[(MHC)*2 + a2l][NH], 0, 0, 0);                   \
    __builtin_amdgcn_s_setprio(0);                                            \
    VM;                                                                       \
    BAR();                                                                    \
  } while (0)

  const int NT = 2 * nks;    // 20 / 30 / 40 (always even)
  int tt = 0, ks = 0;        // tt local 0..1

  // ---- prologue: tile0 -> buf0, order [A0,B0,B1,A1] ----
  {
    const u16* sA0 = xrow + (size_t)(tpair * 2) * (256 * CINP);
    STAGE(sA0, CINP, A0s, 0);
    STAGE(Wg,  Kp,   B0s, 0);
    STAGE(Wg,  Kp,   B0s, 1);
    STAGE(sA0, CINP, A0s, 1);
  }
  asm volatile("s_waitcnt vmcnt(4)" ::: "memory");
  BAR();

  // ---- steady K-loop (tiles 0 .. NT-2) ----
  for (int s = 0; s < NT - 1; s++) {
    int ks2 = ks + 1, tt2 = tt;
    if (ks2 == nks) { ks2 = 0; tt2++; }
    const u16* sA = xrow + (size_t)(tpair * 2 + tt2) * (256 * CINP) + ks2 * 64;
    const u16* sB = Wg + ks2 * 64;
    u16* cA = (s & 1) ? A1s : A0s;
    u16* cB = (s & 1) ? B1s : B0s;
    u16* nA = (s & 1) ? A0s : A1s;
    u16* nB = (s & 1) ? B0s : B1s;

    PHASE(cA, cB, 0, 0, 1, 1, STAGE(sA, CINP, nA, 0),
          asm volatile("s_waitcnt vmcnt(4)" ::: "memory"));
    PHASE(cA, cB, 0, 1, 0, 1, STAGE(sB, Kp,   nB, 0),
          asm volatile("s_waitcnt vmcnt(4)" ::: "memory"));
    PHASE(cA, cB, 1, 0, 1, 0, STAGE(sB, Kp,   nB, 1),
          ((void)0));
    PHASE(cA, cB, 1, 1, 0, 0, STAGE(sA, CINP, nA, 1),
          asm volatile("s_waitcnt vmcnt(4) lgkmcnt(0)" ::: "memory"));

    if (++ks == nks) { FOLD(tpair * 2 + tt); ks = 0; tt++; }
  }

  // ---- peeled last tile (reads buf1; no staging; drain 2 -> 0) ----
  {
    u16* cA = A1s;   // NT even -> last tile parity 1
    u16* cB = B1s;
    PHASE(cA, cB, 0, 0, 1, 1, ((void)0),
          asm volatile("s_waitcnt vmcnt(2)" ::: "memory"));
    PHASE(cA, cB, 0, 1, 0, 1, ((void)0),
          asm volatile("s_waitcnt vmcnt(0)" ::: "memory"));
    PHASE(cA, cB, 1, 0, 1, 0, ((void)0), ((void)0));
    PHASE(cA, cB, 1, 1, 0, 0, ((void)0),
          asm volatile("s_waitcnt lgkmcnt(0)" ::: "memory"));
    FOLD(tpair * 2 + tt);
  }
#undef PHASE

  // ---- epilogue: cross-hi max, bias+relu, atomicMax combine ----
  const float* bias = (g == 0) ? b2v : (g == 1) ? b3v : b4v;
  #pragma unroll
  for (int b2 = 0; b2 < 2; b2++) {
    float v = rmax[b2];
    v = fmaxf(v, __shfl_xor(v, 32));
    if (lane < 32) {
      int ch = chblk * BN + (b2 * 4 + wc) * 32 + lane;
      if (ch < NCH) {
        int n = ch / ODIM, o = ch - n * ODIM;
        float r = fmaxf(v + bias[ch], 0.f);
        atomicMax((u32*)&out[b * (ODIM * 180) + o * 180 + g * 60 + n],
                  __float_as_uint(r));
      }
    }
  }
}

extern "C" void kernel_launch(void* const* d_in, const int* in_sizes, int n_in,
                              void* d_out, int out_size, void* d_ws, size_t ws_size,
                              hipStream_t stream) {
  const float* x  = (const float*)d_in[0];
  const float* W2 = (const float*)d_in[1];
  const float* b2 = (const float*)d_in[2];
  const float* W3 = (const float*)d_in[3];
  const float* b3 = (const float*)d_in[4];
  const float* W4 = (const float*)d_in[5];
  const float* b4 = (const float*)d_in[6];
  float* out = (float*)d_out;

  u16* xb = (u16*)d_ws;            // XELP bf16 (10.5 MB)
  u16* wb = xb + XELP;             // NCHP*(640+960+1280) bf16 (35.4 MB)

  zero_out_kernel<<<(OUTN + 255) / 256, 256, 0, stream>>>(out);
  cvt_x_kernel<<<XELP / (256 * 8), 256, 0, stream>>>(x, xb);
  repack_w_kernel<<<dim3(NCHP, 3), 256, 0, stream>>>(W2, W3, W4, wb);
  gemm_max_kernel<<<dim3(2304), 512, 0, stream>>>(xb, wb, b2, b3, b4, out);
}

// Round 7
// 537.487 us; speedup vs baseline: 1.1246x; 1.1246x over previous
//
#include <hip/hip_runtime.h>
#include <cstdint>
#include <cstddef>

typedef unsigned short u16;
typedef unsigned int   u32;
typedef __attribute__((ext_vector_type(8))) short bf16x8;
typedef __attribute__((ext_vector_type(4))) float f32x4;

#define NB   16
#define LL   1024
#define CIN  300
#define CINP 320              /* padded channels: rows 640B, 16B aligned */
#define XPBP (LL*CINP)        /* 327680 elems per batch */
#define XELP (NB*XPBP)        /* 5242880 */
#define NCH  6000
#define NCHP 6144             /* padded to 24*256 */
#define ODIM 100

#define BM 256
#define BN 256
#define BK 64

__device__ __forceinline__ u16 f2bf(float f) {
  union { float f; u32 u; } v; v.f = f;
  return (u16)((v.u + 0x7FFFu + ((v.u >> 16) & 1u)) >> 16);   // RNE, inputs finite
}

typedef __attribute__((address_space(1))) const unsigned int gu32;
typedef __attribute__((address_space(3))) unsigned int lu32;
__device__ __forceinline__ void gload_lds16(const void* g, void* l) {
  __builtin_amdgcn_global_load_lds((gu32*)g, (lu32*)l, 16, 0, 0);
}

#define BAR() asm volatile("s_barrier" ::: "memory")
#define VM2  asm volatile("s_waitcnt vmcnt(2)" ::: "memory")
#define VM0  asm volatile("s_waitcnt vmcnt(0)" ::: "memory")

// ---- x [16,1024,300] f32 -> xb [16,1024,320] bf16 (zero-pad channels) ----
__global__ void cvt_x_kernel(const float* __restrict__ x, u16* __restrict__ xb) {
  int i8 = (blockIdx.x * 256 + threadIdx.x) * 8;   // grid = XELP/(256*8) = 2560
  int row = i8 / CINP;
  int col = i8 - row * CINP;
  const float* src = x + (size_t)row * CIN + col;
  u16 e[8];
  if (col + 8 <= CIN) {
    float4 a = *(const float4*)src;
    float4 b = *(const float4*)(src + 4);
    e[0]=f2bf(a.x); e[1]=f2bf(a.y); e[2]=f2bf(a.z); e[3]=f2bf(a.w);
    e[4]=f2bf(b.x); e[5]=f2bf(b.y); e[6]=f2bf(b.z); e[7]=f2bf(b.w);
  } else {
    #pragma unroll
    for (int j = 0; j < 8; j++)
      e[j] = (col + j < CIN) ? f2bf(src[j]) : (u16)0;
  }
  uint4 o;
  o.x = (u32)e[0] | ((u32)e[1] << 16);
  o.y = (u32)e[2] | ((u32)e[3] << 16);
  o.z = (u32)e[4] | ((u32)e[5] << 16);
  o.w = (u32)e[6] | ((u32)e[7] << 16);
  *(uint4*)(xb + i8) = o;
}

// ---- W[n,o,c,j] f32 -> Wb[no][kp = j*320 + c] bf16 (zeros c>=300, no>=6000)
__global__ void repack_w_kernel(const float* __restrict__ W2, const float* __restrict__ W3,
                                const float* __restrict__ W4, u16* __restrict__ wb) {
  int g = blockIdx.y;
  int kk = g + 2;
  int Kp = kk * CINP;
  int woff = (g == 0) ? 0 : (g == 1) ? NCHP*640 : NCHP*(640+960);
  const float* W = (g == 0) ? W2 : (g == 1) ? W3 : W4;
  int no = blockIdx.x;                       // 0..6143
  u16* dst = wb + (size_t)woff + (size_t)no * Kp;
  const float* src = W + (size_t)no * (CIN * kk);
  for (int kp = threadIdx.x; kp < Kp; kp += 256) {
    int j = kp / CINP, c = kp - j * CINP;
    u16 v = 0;
    if (no < NCH && c < CIN) v = f2bf(src[c * kk + j]);
    dst[kp] = v;
  }
}

// ---- fused GEMM + running-max + bias + relu ------------------------------
// 256^2 8-phase (T2+T3+T4+T5) with TAIL-READ schedule: each phase's frags
// are ds_read at the END of the previous phase (post-vmcnt, pre-barrier),
// so MFMA operands are in-register when the leading barrier opens.
// Certification chain (all-waves vmcnt + barrier BEFORE any cross-wave read):
//   ph3-end vmcnt(2) -> {nA0,nB0} certified for ph4-tail reads
//   ph4-end vmcnt(2) -> {nB1}     certified for ph1-tail read
//   ph1-end vmcnt(2) -> {nA1}     certified for ph2-tail read
// WAR on buffer reuse closed by compiler lgkm waits at each MFMA.
__global__ __launch_bounds__(512, 1)
void gemm_max_kernel(const u16* __restrict__ xb, const u16* __restrict__ wb,
                     const float* __restrict__ b2v, const float* __restrict__ b3v,
                     const float* __restrict__ b4v, float* __restrict__ out) {
  // LPT remap: ids 0..383 -> g=2, 384..767 -> g=1, 768..1151 -> g=0
  const int id    = blockIdx.x;
  const int g     = 2 - (id / 384);
  const int id2   = id % 384;
  const int b     = id2 / 24;      // 0..15
  const int chblk = id2 % 24;      // 0..23
  const int Kp    = (g + 2) * CINP;                 // 640 / 960 / 1280
  const int nks   = Kp >> 6;                        // 10 / 15 / 20
  const int woff  = (g == 0) ? 0 : (g == 1) ? NCHP*640 : NCHP*(640+960);
  const int Lt    = LL - (g + 2) + 1;

  __shared__ __align__(16) u16 smem[4 * 16384];     // 128 KiB
  u16* A0s = smem;
  u16* B0s = smem + 16384;
  u16* A1s = smem + 32768;
  u16* B1s = smem + 49152;

  const int tid  = threadIdx.x;
  const int lane = tid & 63;
  const int w    = tid >> 6;       // 0..7
  const int wr   = w >> 2;         // 0..1 : M interleave
  const int wc   = w & 3;          // 0..3 : N interleave

  const u16* __restrict__ xrow = xb + (size_t)b * XPBP;
  const u16* __restrict__ Wg   = wb + (size_t)woff + (size_t)chblk * BN * Kp;

  // stage one 128x64 half: linear LDS dest (wave-uniform base), inverse-swizzled src
  auto STAGE = [&](const u16* src, int stride, u16* buf, int half) {
    #pragma unroll
    for (int i = 0; i < 2; i++) {
      int c = i * 512 + w * 64 + lane;                  // chunk 0..1023
      int row128 = c >> 3;
      int colb = ((c & 7) * 16) ^ ((row128 & 7) << 4);  // inverse swizzle (involution)
      gload_lds16(src + (size_t)(half * 128 + row128) * stride + (colb >> 1),
                  buf + half * 8192 + i * 4096 + w * 512);
    }
  };

  // swizzled fragment read: group grp (16 rows), ksub k
  auto FR = [&](const u16* buf, int grp, int k) -> bf16x8 {
    int row  = grp * 16 + (lane & 15);
    int colb = (k * 64 + ((lane >> 4) << 4)) ^ ((lane & 7) << 4);  // row&7 == lane&7
    return *(const bf16x8*)(buf + row * 64 + (colb >> 1));
  };

  f32x4 acc[8][4];
  #pragma unroll
  for (int mi = 0; mi < 8; mi++)
    #pragma unroll
    for (int ni = 0; ni < 4; ni++)
      acc[mi][ni] = (f32x4){0.f, 0.f, 0.f, 0.f};

  bf16x8 afrA[4][2];      // A-half-0 frags (used ph1, ph2)
  bf16x8 afrB[4][2];      // A-half-1 frags (used ph3, ph4)
  bf16x8 bfr[2][2][2];    // [nh][b2][k2]
  float rmax[4] = { -1e30f, -1e30f, -1e30f, -1e30f };

  auto FOLD = [&](int ttf) {
    #pragma unroll
    for (int mi = 0; mi < 8; mi++) {
      int tb = ttf * 256 + (mi * 2 + wr) * 16 + ((lane >> 4) << 2);
      #pragma unroll
      for (int r = 0; r < 4; r++) {
        bool ok = (tb + r) < Lt;
        #pragma unroll
        for (int ni = 0; ni < 4; ni++)
          if (ok) rmax[ni] = fmaxf(rmax[ni], acc[mi][ni][r]);
      }
      #pragma unroll
      for (int ni = 0; ni < 4; ni++)
        acc[mi][ni] = (f32x4){0.f, 0.f, 0.f, 0.f};
    }
  };

#define READ_A(DST, BUF, MH) do {                                             \
    _Pragma("unroll")                                                         \
    for (int a2 = 0; a2 < 4; a2++) {                                          \
      _Pragma("unroll")                                                       \
      for (int k2 = 0; k2 < 2; k2++)                                          \
        DST[a2][k2] = FR(BUF, ((MH)*4 + a2) * 2 + wr, k2);                    \
    }                                                                         \
  } while (0)

#define READ_B(NH, BUF) do {                                                  \
    _Pragma("unroll")                                                         \
    for (int b2 = 0; b2 < 2; b2++) {                                          \
      _Pragma("unroll")                                                       \
      for (int k2 = 0; k2 < 2; k2++)                                          \
        bfr[NH][b2][k2] = FR(BUF, ((NH)*2 + b2) * 4 + wc, k2);                \
    }                                                                         \
  } while (0)

#define MFMAQ(MH, NH, A) do {                                                 \
    __builtin_amdgcn_s_setprio(1);                                            \
    _Pragma("unroll")                                                         \
    for (int a2 = 0; a2 < 4; a2++)                                            \
      _Pragma("unroll")                                                       \
      for (int b2 = 0; b2 < 2; b2++)                                          \
        _Pragma("unroll")                                                     \
        for (int k2 = 0; k2 < 2; k2++)                                        \
          acc[(MH)*4 + a2][(NH)*2 + b2] =                                     \
            __builtin_amdgcn_mfma_f32_16x16x32_bf16(A[a2][k2],                \
              bfr[NH][b2][k2], acc[(MH)*4 + a2][(NH)*2 + b2], 0, 0, 0);       \
    __builtin_amdgcn_s_setprio(0);                                            \
  } while (0)

  const int NT = 4 * nks;    // 40 / 60 / 80 (always even)
  int tt = 0, ks = 0;

  // ---- prologue: tile0 -> buf0, order [A-h0, B-h0, B-h1, A-h1] ----
  STAGE(xrow, CINP, A0s, 0);
  STAGE(Wg,   Kp,   B0s, 0);
  STAGE(Wg,   Kp,   B0s, 1);
  STAGE(xrow, CINP, A0s, 1);
  VM2;                       // A-h0, B-h0, B-h1 certified (A-h1 outstanding)
  BAR();
  READ_A(afrA, A0s, 0);
  READ_B(0, B0s);

  // ---- steady K-loop (tiles 0 .. NT-2) ----
  for (int s = 0; s < NT - 1; s++) {
    int ks2 = ks + 1, tt2 = tt;
    if (ks2 == nks) { ks2 = 0; tt2++; }
    const u16* sA = xrow + (size_t)tt2 * (256 * CINP) + ks2 * 64;
    const u16* sB = Wg + ks2 * 64;
    u16* cA = (s & 1) ? A1s : A0s;
    u16* cB = (s & 1) ? B1s : B0s;
    u16* nA = (s & 1) ? A0s : A1s;
    u16* nB = (s & 1) ? B0s : B1s;

    // ph1
    STAGE(sA, CINP, nA, 0);
    BAR();
    MFMAQ(0, 0, afrA);
    VM2;                     // certify cur A-h1 (for ph2-tail)
    READ_B(1, cB);           // cur B-h1 (certified at prev ph4-end)
    BAR();
    // ph2
    STAGE(sB, Kp, nB, 0);
    BAR();
    MFMAQ(0, 1, afrA);
    READ_A(afrB, cA, 1);     // cur A-h1 (certified at ph1-end)
    BAR();
    // ph3
    STAGE(sB, Kp, nB, 1);
    BAR();
    MFMAQ(1, 0, afrB);
    VM2;                     // certify nA-h0, nB-h0 (for ph4-tail)
    BAR();
    // ph4
    STAGE(sA, CINP, nA, 1);
    BAR();
    MFMAQ(1, 1, afrB);
    VM2;                     // certify nB-h1 (for next ph1-tail)
    READ_A(afrA, nA, 0);     // next A-h0 (certified at ph3-end)
    READ_B(0, nB);           // next B-h0 (certified at ph3-end)
    BAR();

    if (++ks == nks) { FOLD(tt); ks = 0; tt++; }
  }

  // ---- peeled last tile (reads buf1; no staging; drain to 0) ----
  {
    MFMAQ(0, 0, afrA);
    VM0;                     // certify A-h1 (last outstanding)
    READ_B(1, B1s);          // B-h1 (certified at last steady ph4-end)
    BAR();
    MFMAQ(0, 1, afrA);
    READ_A(afrB, A1s, 1);    // A-h1 (certified at VM0 + BAR)
    MFMAQ(1, 0, afrB);
    MFMAQ(1, 1, afrB);
    FOLD(tt);
  }
#undef READ_A
#undef READ_B
#undef MFMAQ

  // ---- epilogue: intra-wave max, cross-wave (wr pair) combine, bias+relu ----
  float cv[4];
  #pragma unroll
  for (int ni = 0; ni < 4; ni++) {
    float v = rmax[ni];
    v = fmaxf(v, __shfl_xor(v, 16));
    v = fmaxf(v, __shfl_xor(v, 32));
    cv[ni] = v;
  }
  __syncthreads();                    // full drain; smem reusable
  float* red = (float*)smem;          // 512 floats: [wr][gn*16 + col]
  if (lane < 16) {
    #pragma unroll
    for (int ni = 0; ni < 4; ni++)
      red[wr * 256 + (ni * 4 + wc) * 16 + lane] = cv[ni];
  }
  __syncthreads();
  const float* bias = (g == 0) ? b2v : (g == 1) ? b3v : b4v;
  if (tid < 256) {
    float v = fmaxf(red[tid], red[256 + tid]);
    int ch = chblk * BN + tid;
    if (ch < NCH) {
      int n = ch / ODIM, o = ch - n * ODIM;
      out[b * (ODIM * 180) + o * 180 + g * 60 + n] = fmaxf(v + bias[ch], 0.f);
    }
  }
}

extern "C" void kernel_launch(void* const* d_in, const int* in_sizes, int n_in,
                              void* d_out, int out_size, void* d_ws, size_t ws_size,
                              hipStream_t stream) {
  const float* x  = (const float*)d_in[0];
  const float* W2 = (const float*)d_in[1];
  const float* b2 = (const float*)d_in[2];
  const float* W3 = (const float*)d_in[3];
  const float* b3 = (const float*)d_in[4];
  const float* W4 = (const float*)d_in[5];
  const float* b4 = (const float*)d_in[6];
  float* out = (float*)d_out;

  u16* xb = (u16*)d_ws;            // XELP bf16 (10.5 MB)
  u16* wb = xb + XELP;             // NCHP*(640+960+1280) bf16 (35.4 MB)

  cvt_x_kernel<<<XELP / (256 * 8), 256, 0, stream>>>(x, xb);
  repack_w_kernel<<<dim3(NCHP, 3), 256, 0, stream>>>(W2, W3, W4, wb);
  gemm_max_kernel<<<dim3(1152), 512, 0, stream>>>(xb, wb, b2, b3, b4, out);
}